// Round 6
// baseline (111.321 us; speedup 1.0000x reference)
//
#include <hip/hip_runtime.h>
#include <hip/hip_fp16.h>
#include <math.h>

#define VOC      512
#define EMB      128
#define L_SEQ    32
#define NWORDS   16384
#define NCOL     416     // 16*(2+4+4+8+8) padded cols
#define WPB      128     // words per conv block
#define SCP      130     // sc pitch (ushorts)

// Seg-major PE subtables (halves), 512 rows, taps padded to jpad (pad=0).
//   seg0 k=2 rowH=32   base 0       seg1 k=3 rowH=64  base 16384
//   seg2 k=4 rowH=64   base 49152   seg3 k=5 rowH=128 base 81920
//   seg4 k=6 rowH=128  base 147456  total 212992 halves = 425984 B
// Unk (<0) chars -> id 512 -> zero row materialized in LDS by conv_max.
__device__ __constant__ int SEGBASE_H[5] = {0, 16384, 49152, 81920, 147456};
__device__ __constant__ int SEGW_H[5]    = {32, 64, 64, 128, 128};
__device__ __constant__ int CCSHIFT[5]   = {1, 2, 2, 3, 3};  // int4 chunks/half-row = 1<<cc

// -------- Kernel A: pack weights to Wt[i][col] (fp32) --------
__global__ __launch_bounds__(NCOL) void pack_wt(
    const float* __restrict__ w2, const float* __restrict__ w3,
    const float* __restrict__ w4, const float* __restrict__ w5,
    const float* __restrict__ w6,
    float* __restrict__ wt)
{
    const int i   = blockIdx.x;      // input channel
    const int col = threadIdx.x;     // 0..415

    int k, jpad, base; const float* w;
    if (col < 32)       { k = 2; jpad = 2; base = 0;   w = w2; }
    else if (col < 96)  { k = 3; jpad = 4; base = 32;  w = w3; }
    else if (col < 160) { k = 4; jpad = 4; base = 96;  w = w4; }
    else if (col < 288) { k = 5; jpad = 8; base = 160; w = w5; }
    else                { k = 6; jpad = 8; base = 288; w = w6; }

    const int r  = col - base;
    const int ol = (jpad == 2) ? (r >> 1) : (jpad == 4) ? (r >> 2) : (r >> 3);
    const int j  = r & (jpad - 1);

    wt[i * NCOL + col] = (j < k) ? w[(ol * EMB + i) * k + j] : 0.f;
}

// -------- Kernel B: PE16 = emb @ Wt, 4 chars/block, seg-major out --------
__device__ __forceinline__ void col_map(int col, int& seg, int& local) {
    if (col < 32)       { seg = 0; local = col; }
    else if (col < 96)  { seg = 1; local = col - 32; }
    else if (col < 160) { seg = 2; local = col - 96; }
    else if (col < 288) { seg = 3; local = col - 160; }
    else                { seg = 4; local = col - 288; }
}

__global__ __launch_bounds__(512) void build_pe16(
    const float* __restrict__ emb,
    const float* __restrict__ wt,
    __half* __restrict__ pe)
{
    const int c0  = blockIdx.x * 4;
    const int tid = threadIdx.x;

    __shared__ float e[4][EMB];      // 2 KB
    e[tid >> 7][tid & 127] = emb[c0 * EMB + tid];   // 512 = 4*128 exact
    __syncthreads();
    if (tid >= NCOL) return;

    float s[4] = {0.f, 0.f, 0.f, 0.f};
    #pragma unroll 8
    for (int i = 0; i < EMB; ++i) {
        float wv = wt[i * NCOL + tid];               // coalesced, L2-hot
        #pragma unroll
        for (int wc = 0; wc < 4; ++wc) s[wc] += e[wc][i] * wv;
    }

    int seg, local; col_map(tid, seg, local);
    const int base = SEGBASE_H[seg], segw = SEGW_H[seg];
    #pragma unroll
    for (int wc = 0; wc < 4; ++wc)
        pe[base + (c0 + wc) * segw + local] = __float2half(s[wc]);
}

// -------- Kernel C: filter-split LDS tables, rolling-window conv+max -----
__device__ __forceinline__ float2 h2tof2(int u) {
    return __half22float2(__builtin_bit_cast(__half2, u));
}

template<int K> struct LdT;
template<> struct LdT<2> { using T = int;  };
template<> struct LdT<3> { using T = int2; };
template<> struct LdT<4> { using T = int2; };
template<> struct LdT<5> { using T = int4; };
template<> struct LdT<6> { using T = int4; };

template<int K>
__device__ __forceinline__ void unpack(typename LdT<K>::T q, float* v) {
    if constexpr (K == 2) {
        float2 f = h2tof2(q); v[0] = f.x; v[1] = f.y;
    } else if constexpr (K == 3) {
        float2 f0 = h2tof2(q.x), f1 = h2tof2(q.y);
        v[0] = f0.x; v[1] = f0.y; v[2] = f1.x;
    } else if constexpr (K == 4) {
        float2 f0 = h2tof2(q.x), f1 = h2tof2(q.y);
        v[0] = f0.x; v[1] = f0.y; v[2] = f1.x; v[3] = f1.y;
    } else if constexpr (K == 5) {
        float2 f0 = h2tof2(q.x), f1 = h2tof2(q.y), f2 = h2tof2(q.z);
        v[0] = f0.x; v[1] = f0.y; v[2] = f1.x; v[3] = f1.y; v[4] = f2.x;
    } else {
        float2 f0 = h2tof2(q.x), f1 = h2tof2(q.y), f2 = h2tof2(q.z);
        v[0] = f0.x; v[1] = f0.y; v[2] = f1.x; v[3] = f1.y;
        v[4] = f2.x; v[5] = f2.y;
    }
}

// Rolling-window conv: win[t%K] accumulates output t; t closes (fmax) when
// its last tap arrives; slot is re-initialized to bias one step later.
// All indices/guards are compile-time under the full unroll.
template<int K, int PAD, int SHIFT, int JPADB>
__device__ __forceinline__ float convseg(const char* __restrict__ tab,
                                         const ushort* __restrict__ sc,
                                         int w, int ol8, float bias)
{
    using LT = typename LdT<K>::T;
    constexpr int LOUT = L_SEQ + 2 * PAD - K + 1;
    const int lb = ol8 * JPADB;

    float win[K];
    #pragma unroll
    for (int i = 0; i < K; ++i) win[i] = bias;
    float m = -INFINITY;

    #pragma unroll
    for (int g = 0; g < 4; ++g) {
        int off[8];
        #pragma unroll
        for (int u = 0; u < 8; ++u)
            off[u] = ((int)sc[(g * 8 + u) * SCP + w] << SHIFT) + lb;
        LT q[8];
        #pragma unroll
        for (int u = 0; u < 8; ++u)
            q[u] = *(const LT*)(tab + off[u]);
        #pragma unroll
        for (int u = 0; u < 8; ++u) {
            const int tp = g * 8 + u;
            float v[K];
            unpack<K>(q[u], v);
            const int topen = tp + PAD;
            if (topen >= K && topen < LOUT) win[topen % K] = bias;
            #pragma unroll
            for (int j = 0; j < K; ++j) {
                int t = tp + PAD - j;
                if (t >= 0 && t < LOUT) win[t % K] += v[j];
            }
            const int tcl = tp + PAD - (K - 1);
            if (tcl >= 0) m = fmaxf(m, win[((unsigned)tcl) % K]);
        }
    }
    #pragma unroll
    for (int t = L_SEQ + PAD - K + 1; t < LOUT; ++t)   // PAD tail outputs
        m = fmaxf(m, win[((unsigned)t) % K]);
    return m;
}

__global__ __launch_bounds__(1024, 8) void conv_max(
    const int*    __restrict__ word,
    const __half* __restrict__ pe,
    const float* __restrict__ b2, const float* __restrict__ b3,
    const float* __restrict__ b4, const float* __restrict__ b5,
    const float* __restrict__ b6,
    float*       __restrict__ out)
{
    // 65,664 B half-table (513 rows x <=128 B) + 8,320 B sc = 73,984 B
    // -> 2 blocks/CU (160 KiB LDS), 32 waves/CU
    __shared__ __align__(16) int4 tab4[513 * 8];
    __shared__ ushort sc[L_SEQ * SCP];

    const int tid  = threadIdx.x;
    const int type = blockIdx.x % 10;      // interleave types across CUs
    const int tile = blockIdx.x / 10;
    const int seg  = type >> 1;            // 0..4, block-uniform
    const int oh   = type & 1;             // filter half

    const int cc     = 1 << CCSHIFT[seg];            // int4 chunks per half-row
    const int ccsh   = CCSHIFT[seg];
    const int halfB  = cc << 4;                      // bytes per half-row
    const int base_b = SEGBASE_H[seg] * 2 + oh * halfB;
    const char* peb  = (const char*)pe;

    // stage half-table rows 0..511 (coalesced, L2-resident)
    for (int i = tid; i < (512 << ccsh); i += 1024)
        tab4[i] = *(const int4*)(peb + base_b
                                 + ((i >> ccsh) << (ccsh + 5))   // row * 2*halfB
                                 + ((i & (cc - 1)) << 4));
    if (tid < cc) tab4[(512 << ccsh) + tid] = int4{0, 0, 0, 0};  // unk row

    // stage char ids transposed [tp][w] (pitch 130 -> conflict-free)
    const int wbase = tile * WPB;
    #pragma unroll
    for (int r = 0; r < 4; ++r) {
        int i = tid + r * 1024;                      // 0..4095
        int c = word[wbase * L_SEQ + i];             // coalesced
        sc[(i & 31) * SCP + (i >> 5)] = (ushort)(c >= 0 ? c : VOC);
    }
    __syncthreads();

    const int ol8 = tid & 7;               // filter within half
    const int w   = tid >> 3;              // word 0..127
    const float* bp;
    switch (seg) {
        case 0:  bp = b2; break; case 1: bp = b3; break;
        case 2:  bp = b4; break; case 3: bp = b5; break;
        default: bp = b6; break;
    }
    const float bias = bp[oh * 8 + ol8];
    const char* tb = (const char*)tab4;

    float m;
    switch (seg) {
        case 0:  m = convseg<2, 0, 5, 4 >(tb, sc, w, ol8, bias); break;
        case 1:  m = convseg<3, 0, 6, 8 >(tb, sc, w, ol8, bias); break;
        case 2:  m = convseg<4, 1, 6, 8 >(tb, sc, w, ol8, bias); break;
        case 3:  m = convseg<5, 2, 7, 16>(tb, sc, w, ol8, bias); break;
        default: m = convseg<6, 3, 7, 16>(tb, sc, w, ol8, bias); break;
    }
    out[(wbase + w) * 80 + (seg << 4) + (oh << 3) + ol8] = m;
}

extern "C" void kernel_launch(void* const* d_in, const int* in_sizes, int n_in,
                              void* d_out, int out_size, void* d_ws, size_t ws_size,
                              hipStream_t stream)
{
    const int*   word = (const int*)  d_in[0];
    const float* emb  = (const float*)d_in[1];
    const float* w2   = (const float*)d_in[2];
    const float* b2   = (const float*)d_in[3];
    const float* w3   = (const float*)d_in[4];
    const float* b3   = (const float*)d_in[5];
    const float* w4   = (const float*)d_in[6];
    const float* b4   = (const float*)d_in[7];
    const float* w5   = (const float*)d_in[8];
    const float* b5   = (const float*)d_in[9];
    const float* w6   = (const float*)d_in[10];
    const float* b6   = (const float*)d_in[11];
    float* out = (float*)d_out;

    // ws: pe16 seg-major [425,984 B], Wt fp32 at +430,080 [212,992 B]
    __half* pe16 = (__half*)d_ws;
    float*  wt   = (float*)((char*)d_ws + 430080);

    pack_wt<<<EMB, NCOL, 0, stream>>>(w2, w3, w4, w5, w6, wt);

    build_pe16<<<VOC / 4, 512, 0, stream>>>(emb, wt, pe16);

    conv_max<<<10 * (NWORDS / WPB), 1024, 0, stream>>>(
        word, pe16, b2, b3, b4, b5, b6, out);
}

// Round 7
// 107.355 us; speedup vs baseline: 1.0369x; 1.0369x over previous
//
#include <hip/hip_runtime.h>
#include <hip/hip_fp16.h>
#include <math.h>

#define VOC      512
#define EMB      128
#define L_SEQ    32
#define NWORDS   16384
#define NCOL     416     // 16*(2+4+4+8+8) padded cols
#define WPB      128     // words per conv block
#define SCPITCH  129     // sc row pitch (ints) -> conflict-free transpose

// Seg-major PE subtables (halves), taps padded to jpad, zeros for j>=k.
//   seg0 k=2 w=32H  base 0        seg1 k=3 w=64H  base 16416
//   seg2 k=4 w=64H  base 49248    seg3 k=5 w=128H base 82080
//   seg4 k=6 w=128H base 147744   total 213408 halves = 426816 B
// Row index VOC (512) in each subtable is all-zero (unk chars).
__device__ __constant__ int SEGBASE_H[5] = {0, 16416, 49248, 82080, 147744};
__device__ __constant__ int SEGW_H[5]    = {32, 64, 64, 128, 128};

// -------- Kernel A: pack weights to Wt[i][col] (fp32) --------
__global__ __launch_bounds__(NCOL) void pack_wt(
    const float* __restrict__ w2, const float* __restrict__ w3,
    const float* __restrict__ w4, const float* __restrict__ w5,
    const float* __restrict__ w6,
    float* __restrict__ wt)
{
    const int i   = blockIdx.x;      // input channel
    const int col = threadIdx.x;     // 0..415

    int k, jpad, base; const float* w;
    if (col < 32)       { k = 2; jpad = 2; base = 0;   w = w2; }
    else if (col < 96)  { k = 3; jpad = 4; base = 32;  w = w3; }
    else if (col < 160) { k = 4; jpad = 4; base = 96;  w = w4; }
    else if (col < 288) { k = 5; jpad = 8; base = 160; w = w5; }
    else                { k = 6; jpad = 8; base = 288; w = w6; }

    const int r  = col - base;
    const int ol = (jpad == 2) ? (r >> 1) : (jpad == 4) ? (r >> 2) : (r >> 3);
    const int j  = r & (jpad - 1);

    wt[i * NCOL + col] = (j < k) ? w[(ol * EMB + i) * k + j] : 0.f;
}

// -------- Kernel B: one block per char; write seg-major fp16 subtables ---
__device__ __forceinline__ void col_map(int col, int& seg, int& local) {
    if (col < 32)       { seg = 0; local = col; }
    else if (col < 96)  { seg = 1; local = col - 32; }
    else if (col < 160) { seg = 2; local = col - 96; }
    else if (col < 288) { seg = 3; local = col - 160; }
    else                { seg = 4; local = col - 288; }
}

__global__ __launch_bounds__(512) void build_pe16(
    const float* __restrict__ emb,
    const float* __restrict__ wt,
    __half* __restrict__ pe)
{
    const int c   = blockIdx.x;     // 0..512 (512 = zero row)
    const int tid = threadIdx.x;

    if (c == VOC) {
        if (tid < NCOL) {
            int seg, local; col_map(tid, seg, local);
            pe[SEGBASE_H[seg] + VOC * SEGW_H[seg] + local] = __float2half(0.f);
        }
        return;
    }

    __shared__ float e[EMB];
    if (tid < EMB) e[tid] = emb[c * EMB + tid];
    __syncthreads();
    if (tid >= NCOL) return;

    float s = 0.f;
    #pragma unroll 8
    for (int i = 0; i < EMB; ++i) s += e[i] * wt[i * NCOL + tid];

    int seg, local; col_map(tid, seg, local);
    pe[SEGBASE_H[seg] + c * SEGW_H[seg] + local] = __float2half(s);
}

// -------- Kernel C: LDS-resident subtable conv + max --------
template<int K> struct LdT;
template<> struct LdT<2> { using T = int;  };
template<> struct LdT<3> { using T = int2; };
template<> struct LdT<4> { using T = int2; };
template<> struct LdT<5> { using T = int4; };
template<> struct LdT<6> { using T = int4; };

// unpack to raw halves; accumulation uses fmaf((float)h, 1.0f, acc) so the
// compiler can fuse convert+add into v_fma_mix_f32.
template<int K>
__device__ __forceinline__ void unpackh(typename LdT<K>::T q, __half* v) {
    if constexpr (K == 2) {
        __half2 h = __builtin_bit_cast(__half2, q);
        v[0] = h.x; v[1] = h.y;
    } else if constexpr (K == 3) {
        __half2 h0 = __builtin_bit_cast(__half2, q.x);
        __half2 h1 = __builtin_bit_cast(__half2, q.y);
        v[0] = h0.x; v[1] = h0.y; v[2] = h1.x;
    } else if constexpr (K == 4) {
        __half2 h0 = __builtin_bit_cast(__half2, q.x);
        __half2 h1 = __builtin_bit_cast(__half2, q.y);
        v[0] = h0.x; v[1] = h0.y; v[2] = h1.x; v[3] = h1.y;
    } else if constexpr (K == 5) {
        __half2 h0 = __builtin_bit_cast(__half2, q.x);
        __half2 h1 = __builtin_bit_cast(__half2, q.y);
        __half2 h2 = __builtin_bit_cast(__half2, q.z);
        v[0] = h0.x; v[1] = h0.y; v[2] = h1.x; v[3] = h1.y; v[4] = h2.x;
    } else {
        __half2 h0 = __builtin_bit_cast(__half2, q.x);
        __half2 h1 = __builtin_bit_cast(__half2, q.y);
        __half2 h2 = __builtin_bit_cast(__half2, q.z);
        v[0] = h0.x; v[1] = h0.y; v[2] = h1.x; v[3] = h1.y;
        v[4] = h2.x; v[5] = h2.y;
    }
}

// tab: LDS subtable (rows of SEGW bytes, bank-aligned). sc: byte offsets.
template<int K, int PAD, int LANEB>
__device__ __forceinline__ float convseg(const char* __restrict__ tab,
                                         const int* __restrict__ sc,
                                         int w, int ol, float bias)
{
    using LT = typename LdT<K>::T;
    constexpr int LOUT = L_SEQ + 2 * PAD - K + 1;
    const int lb = ol * LANEB;

    float s[LOUT];
    #pragma unroll
    for (int t = 0; t < LOUT; ++t) s[t] = bias;

    #pragma unroll
    for (int g = 0; g < 4; ++g) {
        int off[8];
        #pragma unroll
        for (int u = 0; u < 8; ++u)
            off[u] = sc[(g * 8 + u) * SCPITCH + w] + lb;
        LT q[8];
        #pragma unroll
        for (int u = 0; u < 8; ++u)
            q[u] = *(const LT*)(tab + off[u]);
        #pragma unroll
        for (int u = 0; u < 8; ++u) {
            const int tp = g * 8 + u;
            __half v[K];
            unpackh<K>(q[u], v);
            #pragma unroll
            for (int j = 0; j < K; ++j) {
                int t = tp + PAD - j;
                if (t >= 0 && t < LOUT)
                    s[t] = fmaf(__half2float(v[j]), 1.0f, s[t]);  // v_fma_mix
            }
        }
    }

    float m = s[0];
    #pragma unroll
    for (int t = 1; t < LOUT; ++t) m = fmaxf(m, s[t]);
    return m;
}

__global__ __launch_bounds__(1024) void conv_max(
    const int*    __restrict__ word,
    const __half* __restrict__ pe,
    const float* __restrict__ b2, const float* __restrict__ b3,
    const float* __restrict__ b4, const float* __restrict__ b5,
    const float* __restrict__ b6,
    float*       __restrict__ out)
{
    // 131,328 B table + 16,512 B sc = 147,840 B (gfx950 LDS is 160 KiB/WG)
    __shared__ __align__(16) __half tab[65664];
    __shared__ int sc[L_SEQ * SCPITCH];

    const int tid = threadIdx.x;
    // LPT ordering: heavy segments (k=5,6: b128 gathers) in the earliest
    // blocks, lightest (k=2) last -> the 640-on-256-CU tail runs cheap blocks.
    const int grp = blockIdx.x >> 7;          // 0..4 (128 blocks each)
    const int wb  = blockIdx.x & 127;         // tile
    const int seg = (grp == 0) ? 3 : (grp == 1) ? 4
                  : (grp == 2) ? 2 : (grp == 3) ? 1 : 0;   // block-uniform
    const int wbase = wb * WPB;

    const int segwH = SEGW_H[seg];
    const int nI4   = (513 * segwH) >> 3;     // int4 count

    // stage subtable: coalesced, L2-resident
    const int4* src = (const int4*)(pe + SEGBASE_H[seg]);
    int4* dst = (int4*)tab;
    for (int i = tid; i < nI4; i += 1024) dst[i] = src[i];

    // stage char byte-offsets, transposed with pitch 129 (conflict-free)
    const int segwB = segwH * 2;
    #pragma unroll
    for (int r = 0; r < 4; ++r) {
        int i = tid + r * 1024;               // 0..4095
        int c = word[wbase * L_SEQ + i];      // coalesced
        int w = i >> 5, tp = i & 31;
        sc[tp * SCPITCH + w] = (c >= 0 ? c : VOC) * segwB;
    }
    __syncthreads();

    const int ol = tid & 15;                  // filter
    const int w0 = tid >> 4;                  // word 0..63; second +64
    const float* bp;
    switch (seg) {
        case 0:  bp = b2; break; case 1: bp = b3; break;
        case 2:  bp = b4; break; case 3: bp = b5; break;
        default: bp = b6; break;
    }
    const float bias = bp[ol];
    const char* tb = (const char*)tab;

    float m0, m1;
    switch (seg) {
        case 0:  m0 = convseg<2, 0, 4 >(tb, sc, w0,      ol, bias);
                 m1 = convseg<2, 0, 4 >(tb, sc, w0 + 64, ol, bias); break;
        case 1:  m0 = convseg<3, 0, 8 >(tb, sc, w0,      ol, bias);
                 m1 = convseg<3, 0, 8 >(tb, sc, w0 + 64, ol, bias); break;
        case 2:  m0 = convseg<4, 1, 8 >(tb, sc, w0,      ol, bias);
                 m1 = convseg<4, 1, 8 >(tb, sc, w0 + 64, ol, bias); break;
        case 3:  m0 = convseg<5, 2, 16>(tb, sc, w0,      ol, bias);
                 m1 = convseg<5, 2, 16>(tb, sc, w0 + 64, ol, bias); break;
        default: m0 = convseg<6, 3, 16>(tb, sc, w0,      ol, bias);
                 m1 = convseg<6, 3, 16>(tb, sc, w0 + 64, ol, bias); break;
    }
    out[(wbase + w0     ) * 80 + seg * 16 + ol] = m0;
    out[(wbase + w0 + 64) * 80 + seg * 16 + ol] = m1;
}

extern "C" void kernel_launch(void* const* d_in, const int* in_sizes, int n_in,
                              void* d_out, int out_size, void* d_ws, size_t ws_size,
                              hipStream_t stream)
{
    const int*   word = (const int*)  d_in[0];
    const float* emb  = (const float*)d_in[1];
    const float* w2   = (const float*)d_in[2];
    const float* b2   = (const float*)d_in[3];
    const float* w3   = (const float*)d_in[4];
    const float* b3   = (const float*)d_in[5];
    const float* w4   = (const float*)d_in[6];
    const float* b4   = (const float*)d_in[7];
    const float* w5   = (const float*)d_in[8];
    const float* b5   = (const float*)d_in[9];
    const float* w6   = (const float*)d_in[10];
    const float* b6   = (const float*)d_in[11];
    float* out = (float*)d_out;

    // ws: pe16 seg-major [426,816 B], Wt fp32 at +430,080 [212,992 B]
    __half* pe16 = (__half*)d_ws;
    float*  wt   = (float*)((char*)d_ws + 430080);

    pack_wt<<<EMB, NCOL, 0, stream>>>(w2, w3, w4, w5, w6, wt);

    build_pe16<<<VOC + 1, 512, 0, stream>>>(emb, wt, pe16);

    conv_max<<<5 * (NWORDS / WPB), 1024, 0, stream>>>(
        word, pe16, b2, b3, b4, b5, b6, out);
}